// Round 8
// baseline (199.699 us; speedup 1.0000x reference)
//
#include <hip/hip_runtime.h>
#include <math.h>

#define B_ 4
#define S_ 2048
#define G_ 8
#define D_ 128
#define N_ 64
#define ROWS (B_*S_*G_)      // 65536
#define CH 64
#define CLEN 32
#define YOFF (ROWS*D_)       // 8388608

typedef short bf16x8 __attribute__((ext_vector_type(8)));
typedef float f32x4  __attribute__((ext_vector_type(4)));
#define MFMA16(a,b,c) __builtin_amdgcn_mfma_f32_16x16x32_bf16(a,b,c,0,0,0)

__device__ __forceinline__ unsigned short bf16_rtne(float f) {
    unsigned u = __float_as_uint(f);
    unsigned r = (u + 0x7FFFu + ((u >> 16) & 1u)) >> 16;
    return (unsigned short)r;
}
__device__ __forceinline__ void split_bf16(float f, unsigned short &hi, unsigned short &lo) {
    hi = bf16_rtne(f);
    float hif = __uint_as_float(((unsigned)hi) << 16);
    lo = bf16_rtne(f - hif);
}
__device__ __forceinline__ unsigned pk_bf16(float a, float b) {
    unsigned r;
    asm("v_cvt_pk_bf16_f32 %0, %1, %2" : "=v"(r) : "v"(a), "v"(b));
    return r;
}
__device__ __forceinline__ float dot4(float4 a, float4 b) {
    return fmaf(a.x,b.x, fmaf(a.y,b.y, fmaf(a.z,b.z, a.w*b.w)));
}

// ============ k_prep: pre-split weights into MFMA fragment order ============
__global__ __launch_bounds__(256) void k_prep(
    const float* __restrict__ bwr, const float* __restrict__ bwi,
    const float* __restrict__ cwr, const float* __restrict__ cwi,
    unsigned short* __restrict__ wbhi, unsigned short* __restrict__ wblo,
    unsigned short* __restrict__ wchi)
{
    int tid = blockIdx.x * 256 + threadIdx.x;   // [0, 8192)
    if (tid < 4096) {
        int f = tid;
        int lane = f & 63, ks = (f >> 6) & 7, nt = (f >> 9) & 1, w = f >> 10;
        int l15 = lane & 15, quad = lane >> 4;
        int n = w * 32 + nt * 16 + l15;
        int k0 = ks * 32 + quad * 8;
        const float* src; float sgn = 1.f;
        if (n < 64) {
            if (k0 < 128) src = bwr + n * 128 + k0;
            else        { src = bwi + n * 128 + (k0 - 128); sgn = -1.f; }
        } else {
            if (k0 < 128) src = bwi + (n - 64) * 128 + k0;
            else          src = bwr + (n - 64) * 128 + (k0 - 128);
        }
        float4 v0 = *(const float4*)src;
        float4 v1 = *(const float4*)(src + 4);
        float vv[8] = {v0.x,v0.y,v0.z,v0.w,v1.x,v1.y,v1.z,v1.w};
        unsigned short h[8], l[8];
        #pragma unroll
        for (int j = 0; j < 8; j++) split_bf16(vv[j] * sgn, h[j], l[j]);
        #pragma unroll
        for (int j = 0; j < 8; j++) { wbhi[f*8+j] = h[j]; wblo[f*8+j] = l[j]; }
    } else {
        int f = tid - 4096;
        int lane = f & 63, ks = (f >> 6) & 3, nt = (f >> 8) & 3, w = f >> 10;
        int l15 = lane & 15, quad = lane >> 4;
        int n = w * 64 + nt * 16 + l15;
        int d = (n < 128) ? n : (n - 128);
        int k0 = ks * 32 + quad * 8;
        unsigned short h[8];
        #pragma unroll
        for (int j = 0; j < 8; j++) {
            int k = k0 + j, col = k >> 1;
            float val;
            if (n < 128) val = (k & 1) ? -cwi[d * 64 + col] : cwr[d * 64 + col];
            else         val = (k & 1) ?  cwr[d * 64 + col] : cwi[d * 64 + col];
            unsigned short hh, hl; split_bf16(val, hh, hl);
            h[j] = hh;
        }
        #pragma unroll
        for (int j = 0; j < 8; j++) wchi[f*8+j] = h[j];
    }
}

// ============ G1: dt + Bx GEMM + compose. 1 chunk/block, grid 2048 ==========
// Single-rail bf16 B-GEMM; bx written as packed bf16 (vr,vi) u32, contiguous.
#define LDK1 264
__global__ __launch_bounds__(256, 8) void k_g1(
    const float* __restrict__ xr, const float* __restrict__ xi,
    const float* __restrict__ dtw, const float* __restrict__ dtb,
    const float* __restrict__ logAm, const float* __restrict__ Aph,
    const unsigned short* __restrict__ wbhi,
    unsigned* __restrict__ bxp,
    float* __restrict__ dt_mag, float* __restrict__ dt_ph,
    float4* __restrict__ trans)
{
    __shared__ __align__(16) unsigned short Ahi[32 * LDK1];   // 16,896 B
    __shared__ float4 comb[192];                               // 3,072 B
    __shared__ float dms[32], dps[32];                         // 256 B
    float* bxs = (float*)Ahi;   // 32*132 floats, reused after MFMA
    const int t = threadIdx.x;
    const int lane = t & 63, w = t >> 6;
    const int l15 = lane & 15, quad = lane >> 4;
    const int bg = blockIdx.x >> 6, c = blockIdx.x & 63;
    const int g = bg & 7, b = bg >> 3;
    const int crow = (bg * CH + c) * CLEN;

    const int kq = t & 31, k4 = kq * 4;
    float4 w0r = *(const float4*)(dtw + k4);
    float4 w0i = *(const float4*)(dtw + 128 + k4);
    float4 w1r = *(const float4*)(dtw + 256 + k4);
    float4 w1i = *(const float4*)(dtw + 384 + k4);
    float b0 = dtb[0], b1 = dtb[1];
    float nla = -logf(1.0f + __expf(logAm[g * N_ + lane]));
    float aph = Aph[g * N_ + lane];

    const bf16x8* WHp = (const bf16x8*)wbhi + (w * 2) * 512 + lane;
    bf16x8 wh0 = WHp[0];
    bf16x8 wh1 = WHp[512];

    const float* xrb = xr + ((size_t)(b * S_ + c * CLEN) * G_ + g) * 128;
    const float* xib = xi + ((size_t)(b * S_ + c * CLEN) * G_ + g) * 128;

    // -------- stage x -> LDS (bf16 hi rail) + dt partial dots --------
    float pm[4], pp[4];
    #pragma unroll
    for (int i = 0; i < 4; i++) {
        int f = t + 256 * i;
        int m = f >> 5, kk = f & 31;
        float4 a  = ((const float4*)(xrb + m * 1024))[kk];
        float4 bb = ((const float4*)(xib + m * 1024))[kk];
        *(uint2*)&Ahi[m * LDK1 + kk * 4] =
            make_uint2(pk_bf16(a.x, a.y), pk_bf16(a.z, a.w));
        *(uint2*)&Ahi[m * LDK1 + 128 + kk * 4] =
            make_uint2(pk_bf16(bb.x, bb.y), pk_bf16(bb.z, bb.w));
        pm[i] = dot4(a, w0r) + dot4(bb, w0i);
        pp[i] = dot4(a, w1r) + dot4(bb, w1i);
    }
    #pragma unroll
    for (int i = 0; i < 4; i++) {
        float vm = pm[i], vp = pp[i];
        #pragma unroll
        for (int msk = 16; msk >= 1; msk >>= 1) {
            vm += __shfl_xor(vm, msk);
            vp += __shfl_xor(vp, msk);
        }
        if ((t & 31) == 0) {
            int m = (t >> 5) + 8 * i;
            float dm = fminf(fmaxf(__expf(vm + b0), 1e-4f), 2.0f);
            float dp = fminf(fmaxf(__expf(vp + b1), 1e-4f), 2.0f);
            dms[m] = dm; dps[m] = dp;
            dt_mag[crow + m] = dm; dt_ph[crow + m] = dp;
        }
    }
    __syncthreads();

    // -------- Bx GEMM: 1 MFMA per (ks,ms,nt); W streamed, pipelined --------
    f32x4 acc[2][2];
    #pragma unroll
    for (int a = 0; a < 2; a++)
        #pragma unroll
        for (int bq = 0; bq < 2; bq++)
            acc[a][bq] = (f32x4){0.f, 0.f, 0.f, 0.f};
    #pragma unroll
    for (int ks = 0; ks < 8; ks++) {
        bf16x8 nh0, nh1;
        if (ks < 7) {
            nh0 = WHp[(ks + 1) * 64];
            nh1 = WHp[512 + (ks + 1) * 64];
        }
        #pragma unroll
        for (int ms = 0; ms < 2; ms++) {
            int arow = (ms * 16 + l15) * LDK1 + quad * 8;
            bf16x8 ah = *(const bf16x8*)&Ahi[arow + ks * 32];
            acc[ms][0] = MFMA16(ah, wh0, acc[ms][0]);
            acc[ms][1] = MFMA16(ah, wh1, acc[ms][1]);
        }
        if (ks < 7) { wh0 = nh0; wh1 = nh1; }
    }
    __syncthreads();   // staging reads done; Ahi becomes bxs

    // -------- bx (scaled) -> LDS fp32 --------
    #pragma unroll
    for (int ms = 0; ms < 2; ms++)
        #pragma unroll
        for (int nt = 0; nt < 2; nt++) {
            int n = w * 32 + nt * 16 + l15;
            #pragma unroll
            for (int r = 0; r < 4; r++) {
                int m = ms * 16 + quad * 4 + r;
                bxs[m * 132 + n] = acc[ms][nt][r] * dms[m];
            }
        }
    __syncthreads();

    // -------- packed bf16 bx -> global (contiguous 8KB) + compose ----------
    #pragma unroll
    for (int i = 0; i < 8; i++) {
        int e = t + 256 * i;                 // 2048 = 32 rows x 64 n
        int m = e >> 6, n = e & 63;
        bxp[(crow + m) * 64 + n] = pk_bf16(bxs[m * 132 + n], bxs[m * 132 + 64 + n]);
    }
    {
        float Ar = 1.f, Ai = 0.f, Br = 0.f, Bi = 0.f;
        const int base = w * 8;
        #pragma unroll
        for (int tt = 0; tt < 8; tt++) {
            const int m = base + tt;
            float dm = dms[m], dp = dps[m];
            float am  = __expf(dm * nla);
            float ang = dp * aph;
            float cr = am * __cosf(ang), ci = am * __sinf(ang);
            float vr = bxs[m * 132 + lane], vi = bxs[m * 132 + 64 + lane];
            float nAr = cr * Ar - ci * Ai;
            float nAi = cr * Ai + ci * Ar;
            float nBr = cr * Br - ci * Bi + vr;
            float nBi = cr * Bi + ci * Br + vi;
            Ar = nAr; Ai = nAi; Br = nBr; Bi = nBi;
        }
        if (w < 3) comb[w * 64 + lane] = make_float4(Ar, Ai, Br, Bi);
        __syncthreads();
        if (w == 3) {
            float4 cc0 = comb[lane];
            float cAr = cc0.x, cAi = cc0.y, cBr = cc0.z, cBi = cc0.w;
            #pragma unroll
            for (int s = 1; s < 3; s++) {
                float4 ps = comb[s * 64 + lane];
                float nAr = ps.x * cAr - ps.y * cAi;
                float nAi = ps.x * cAi + ps.y * cAr;
                float nBr = ps.x * cBr - ps.y * cBi + ps.z;
                float nBi = ps.x * cBi + ps.y * cBr + ps.w;
                cAr = nAr; cAi = nAi; cBr = nBr; cBi = nBi;
            }
            float fAr = Ar * cAr - Ai * cAi;
            float fAi = Ar * cAi + Ai * cAr;
            float fBr = Ar * cBr - Ai * cBi + Br;
            float fBi = Ar * cBi + Ai * cBr + Bi;
            trans[(bg * CH + c) * 64 + lane] = make_float4(fAr, fAi, fBr, fBi);
        }
    }
}

// ============ scanB2: parallel chunk-level combine ==========================
__global__ __launch_bounds__(256) void k_scanB2(const float4* __restrict__ trans,
    float2* __restrict__ hstart)
{
    int w = threadIdx.x >> 6, lane = threadIdx.x & 63;
    int W = blockIdx.x * 4 + w;              // [0,256)
    int bg = W >> 3;
    int n  = ((W & 7) << 3) + (lane & 7);
    int j  = lane >> 3;                       // segment index
    float pAr[8], pAi[8], pBr[8], pBi[8];
    float Ar = 1.f, Ai = 0.f, Br = 0.f, Bi = 0.f;
    const float4* tp = trans + (bg * CH + j * 8) * 64 + n;
    #pragma unroll
    for (int k = 0; k < 8; k++) {
        pAr[k] = Ar; pAi[k] = Ai; pBr[k] = Br; pBi[k] = Bi;
        float4 T = tp[k * 64];
        float nAr = T.x * Ar - T.y * Ai;
        float nAi = T.x * Ai + T.y * Ar;
        float nBr = T.x * Br - T.y * Bi + T.z;
        float nBi = T.x * Bi + T.y * Br + T.w;
        Ar = nAr; Ai = nAi; Br = nBr; Bi = nBi;
    }
    float hr = 0.f, hi = 0.f, mhr = 0.f, mhi = 0.f;
    #pragma unroll
    for (int j2 = 0; j2 < 8; j2++) {
        if (j2 == j) { mhr = hr; mhi = hi; }
        int src = j2 * 8 + (lane & 7);
        float sAr = __shfl(Ar, src), sAi = __shfl(Ai, src);
        float sBr = __shfl(Br, src), sBi = __shfl(Bi, src);
        float nr = sAr * hr - sAi * hi + sBr;
        float ni = sAr * hi + sAi * hr + sBi;
        float nrm = sqrtf(nr * nr + ni * ni + 1e-8f);
        float sc = fminf(nrm, 100.f) / nrm;
        hr = nr * sc; hi = ni * sc;
    }
    float2* hp = hstart + (bg * CH + j * 8) * 64 + n;
    #pragma unroll
    for (int k = 0; k < 8; k++) {
        float hsr = pAr[k] * mhr - pAi[k] * mhi + pBr[k];
        float hsi = pAr[k] * mhi + pAi[k] * mhr + pBi[k];
        hp[k * 64] = make_float2(hsr, hsi);
    }
}

// ============ SG4: 4-wave segmented scan + y GEMM + LDS-transposed store ====
#define LDK2 152
#define OTS 260   // out-tile LDS row stride (floats), breaks bank alias
__global__ __launch_bounds__(256, 6) void k_sg4(
    const unsigned* __restrict__ bxp,
    const float* __restrict__ dt_mag, const float* __restrict__ dt_ph,
    const float* __restrict__ logAm, const float* __restrict__ Aph,
    const float2* __restrict__ hstart,
    const unsigned short* __restrict__ wchi,
    float* __restrict__ out)
{
    __shared__ __align__(16) unsigned short Ahi[32 * LDK2];   // 9,728 B
    __shared__ __align__(16) unsigned short Alo[32 * LDK2];   // 9,728 B
    __shared__ float4 comb[256];                              // 4,096 B
    float* OT = (float*)Ahi;   // 16*260*4 = 16,640 B, aliased after GEMM reads
    const int t = threadIdx.x;
    const int lane = t & 63, w = t >> 6;
    const int l15 = lane & 15, quad = lane >> 4;
    const int bg = blockIdx.x >> 6, c = blockIdx.x & 63;
    const int g = bg & 7, b = bg >> 3;
    const int base = (bg * CH + c) * CLEN;
    const int s8 = w * 8;

    // -------- prefetch (independent loads, issued up front) ---------------
    unsigned bxv[8];
    #pragma unroll
    for (int s = 0; s < 8; s++)
        bxv[s] = bxp[(base + s8 + s) * 64 + lane];
    float dval = 0.f;
    if (lane < 8)       dval = dt_mag[base + s8 + lane];
    else if (lane < 16) dval = dt_ph[base + s8 + (lane - 8)];
    float2 h0 = hstart[(bg * CH + c) * 64 + lane];
    float nla = -logf(1.0f + __expf(logAm[g * N_ + lane]));
    float aph = Aph[g * N_ + lane];

    // -------- segment prefix composition (8 steps, in registers) ----------
    float paR[8], paI[8], pbR[8], pbI[8];
    {
        float Ar = 1.f, Ai = 0.f, Br = 0.f, Bi = 0.f;
        #pragma unroll
        for (int s = 0; s < 8; s++) {
            float dm = __shfl(dval, s), dp = __shfl(dval, 8 + s);
            float am  = __expf(dm * nla);
            float ang = dp * aph;
            float cr = am * __cosf(ang), ci = am * __sinf(ang);
            unsigned u = bxv[s];
            float vr = __uint_as_float(u << 16);
            float vi = __uint_as_float(u & 0xFFFF0000u);
            float nAr = cr * Ar - ci * Ai;
            float nAi = cr * Ai + ci * Ar;
            float nBr = cr * Br - ci * Bi + vr;
            float nBi = cr * Bi + ci * Br + vi;
            Ar = nAr; Ai = nAi; Br = nBr; Bi = nBi;
            paR[s] = Ar; paI[s] = Ai; pbR[s] = Br; pbI[s] = Bi;
        }
        comb[w * 64 + lane] = make_float4(Ar, Ai, Br, Bi);
    }
    __syncthreads();

    // -------- lookback + materialize h rows -------------------------------
    float Hr = h0.x, Hi = h0.y;
    for (int s2 = 0; s2 < w; s2++) {           // wave-uniform bound
        float4 T = comb[s2 * 64 + lane];
        float nr = T.x * Hr - T.y * Hi + T.z;
        float ni = T.x * Hi + T.y * Hr + T.w;
        Hr = nr; Hi = ni;
    }
    {
        const bool rn = ((c & 7) == 7) && (w == 3);
        #pragma unroll
        for (int s = 0; s < 8; s++) {
            float hr = paR[s] * Hr - paI[s] * Hi + pbR[s];
            float hi = paR[s] * Hi + paI[s] * Hr + pbI[s];
            if (rn && s == 7) {
                float nrm = sqrtf(hr * hr + hi * hi + 1e-8f);
                float scale = fminf(nrm, 100.0f) / nrm;
                hr *= scale; hi *= scale;
            }
            unsigned hp = pk_bf16(hr, hi);
            float rr = hr - __uint_as_float(hp << 16);
            float ri = hi - __uint_as_float(hp & 0xFFFF0000u);
            unsigned lp = pk_bf16(rr, ri);
            int tt = s8 + s;
            *(unsigned*)&Ahi[tt * LDK2 + 2 * lane] = hp;
            *(unsigned*)&Alo[tt * LDK2 + 2 * lane] = lp;
        }
    }
    __syncthreads();

    // -------- y GEMM: M=32, N=256 (wave owns 64 cols), wc streamed ---------
    f32x4 acc[2][4];
    #pragma unroll
    for (int a = 0; a < 2; a++)
        #pragma unroll
        for (int bq = 0; bq < 4; bq++)
            acc[a][bq] = (f32x4){0.f, 0.f, 0.f, 0.f};
    #pragma unroll
    for (int ks = 0; ks < 4; ks++) {
        bf16x8 wc0 = ((const bf16x8*)wchi)[((w * 4 + 0) * 4 + ks) * 64 + lane];
        bf16x8 wc1 = ((const bf16x8*)wchi)[((w * 4 + 1) * 4 + ks) * 64 + lane];
        bf16x8 wc2 = ((const bf16x8*)wchi)[((w * 4 + 2) * 4 + ks) * 64 + lane];
        bf16x8 wc3 = ((const bf16x8*)wchi)[((w * 4 + 3) * 4 + ks) * 64 + lane];
        #pragma unroll
        for (int ms = 0; ms < 2; ms++) {
            int arow = (ms * 16 + l15) * LDK2 + quad * 8;
            bf16x8 ah = *(const bf16x8*)&Ahi[arow + ks * 32];
            bf16x8 al = *(const bf16x8*)&Alo[arow + ks * 32];
            acc[ms][0] = MFMA16(al, wc0, acc[ms][0]);
            acc[ms][0] = MFMA16(ah, wc0, acc[ms][0]);
            acc[ms][1] = MFMA16(al, wc1, acc[ms][1]);
            acc[ms][1] = MFMA16(ah, wc1, acc[ms][1]);
            acc[ms][2] = MFMA16(al, wc2, acc[ms][2]);
            acc[ms][2] = MFMA16(ah, wc2, acc[ms][2]);
            acc[ms][3] = MFMA16(al, wc3, acc[ms][3]);
            acc[ms][3] = MFMA16(ah, wc3, acc[ms][3]);
        }
    }
    __syncthreads();   // all GEMM LDS reads done; Ahi/Alo become OT

    // -------- epilogue: 2 half-tiles via LDS -> 512B-contiguous stores -----
    #pragma unroll 1
    for (int ms = 0; ms < 2; ms++) {
        #pragma unroll
        for (int nt = 0; nt < 4; nt++)
            #pragma unroll
            for (int r = 0; r < 4; r++)
                OT[(quad * 4 + r) * OTS + w * 64 + nt * 16 + l15] = acc[ms][nt][r];
        __syncthreads();
        #pragma unroll
        for (int jj = 0; jj < 4; jj++) {
            int idx = t + 256 * jj;              // [0,1024): 16 rows x 2 planes x 32 f4
            int rl = idx >> 6, rem = idx & 63;
            int plane = rem >> 5, c4 = rem & 31;
            f32x4 v = *(const f32x4*)&OT[rl * OTS + plane * 128 + c4 * 4];
            int srow = (b * S_ + c * CLEN + ms * 16 + rl) * G_ + g;
            float* dst = (plane ? out + YOFF : out) + (size_t)srow * 128 + c4 * 4;
            *(f32x4*)dst = v;
        }
        __syncthreads();
    }
}

extern "C" void kernel_launch(void* const* d_in, const int* in_sizes, int n_in,
                              void* d_out, int out_size, void* d_ws, size_t ws_size,
                              hipStream_t stream) {
    (void)in_sizes; (void)n_in; (void)out_size; (void)ws_size;
    const float* xr    = (const float*)d_in[0];
    const float* xi    = (const float*)d_in[1];
    const float* logAm = (const float*)d_in[2];
    const float* Aph   = (const float*)d_in[3];
    const float* bwr   = (const float*)d_in[4];
    const float* bwi   = (const float*)d_in[5];
    const float* cwr   = (const float*)d_in[6];
    const float* cwi   = (const float*)d_in[7];
    const float* dtw   = (const float*)d_in[8];
    const float* dtb   = (const float*)d_in[9];
    float* out = (float*)d_out;
    float* ws  = (float*)d_ws;

    float*    dt_mag = ws;                      // 65536
    float*    dt_ph  = ws + 65536;              // 65536
    unsigned* bxp    = (unsigned*)(ws + 131072);// 4194304 u32 (16 MB)
    float4*   trans  = (float4*)(ws + 8519680); // 131072 float4
    float2*   hstart = (float2*)(ws + 9043968); // 131072 float2
    unsigned short* wbhi = (unsigned short*)(ws + 9306112); // 32768 shorts
    unsigned short* wblo = wbhi + 32768;
    unsigned short* wchi = wblo + 32768;

    hipLaunchKernelGGL(k_prep,   dim3(32), dim3(256), 0, stream,
                       bwr, bwi, cwr, cwi, wbhi, wblo, wchi);
    hipLaunchKernelGGL(k_g1,     dim3((B_ * G_) * 64), dim3(256), 0, stream,
                       xr, xi, dtw, dtb, logAm, Aph, wbhi,
                       bxp, dt_mag, dt_ph, trans);
    hipLaunchKernelGGL(k_scanB2, dim3(64), dim3(256), 0, stream,
                       trans, hstart);
    hipLaunchKernelGGL(k_sg4,    dim3((B_ * G_) * 64), dim3(256), 0, stream,
                       bxp, dt_mag, dt_ph, logAm, Aph, hstart, wchi, out);
}

// Round 9
// 153.383 us; speedup vs baseline: 1.3020x; 1.3020x over previous
//
#include <hip/hip_runtime.h>
#include <math.h>

#define B_ 4
#define S_ 2048
#define G_ 8
#define D_ 128
#define N_ 64
#define ROWS (B_*S_*G_)      // 65536
#define CH 64
#define CLEN 32
#define YOFF (ROWS*D_)       // 8388608

typedef short bf16x8 __attribute__((ext_vector_type(8)));
typedef float f32x4  __attribute__((ext_vector_type(4)));
#define MFMA16(a,b,c) __builtin_amdgcn_mfma_f32_16x16x32_bf16(a,b,c,0,0,0)

__device__ __forceinline__ unsigned short bf16_rtne(float f) {
    unsigned u = __float_as_uint(f);
    unsigned r = (u + 0x7FFFu + ((u >> 16) & 1u)) >> 16;
    return (unsigned short)r;
}
__device__ __forceinline__ void split_bf16(float f, unsigned short &hi, unsigned short &lo) {
    hi = bf16_rtne(f);
    float hif = __uint_as_float(((unsigned)hi) << 16);
    lo = bf16_rtne(f - hif);
}
__device__ __forceinline__ unsigned pk_bf16(float a, float b) {
    unsigned r;
    asm("v_cvt_pk_bf16_f32 %0, %1, %2" : "=v"(r) : "v"(a), "v"(b));
    return r;
}
__device__ __forceinline__ float dot4(float4 a, float4 b) {
    return fmaf(a.x,b.x, fmaf(a.y,b.y, fmaf(a.z,b.z, a.w*b.w)));
}

// ============ k_prep: pre-split weights into MFMA fragment order ============
__global__ __launch_bounds__(256) void k_prep(
    const float* __restrict__ bwr, const float* __restrict__ bwi,
    const float* __restrict__ cwr, const float* __restrict__ cwi,
    unsigned short* __restrict__ wbhi, unsigned short* __restrict__ wblo,
    unsigned short* __restrict__ wchi)
{
    int tid = blockIdx.x * 256 + threadIdx.x;   // [0, 8192)
    if (tid < 4096) {
        int f = tid;
        int lane = f & 63, ks = (f >> 6) & 7, nt = (f >> 9) & 1, w = f >> 10;
        int l15 = lane & 15, quad = lane >> 4;
        int n = w * 32 + nt * 16 + l15;
        int k0 = ks * 32 + quad * 8;
        const float* src; float sgn = 1.f;
        if (n < 64) {
            if (k0 < 128) src = bwr + n * 128 + k0;
            else        { src = bwi + n * 128 + (k0 - 128); sgn = -1.f; }
        } else {
            if (k0 < 128) src = bwi + (n - 64) * 128 + k0;
            else          src = bwr + (n - 64) * 128 + (k0 - 128);
        }
        float4 v0 = *(const float4*)src;
        float4 v1 = *(const float4*)(src + 4);
        float vv[8] = {v0.x,v0.y,v0.z,v0.w,v1.x,v1.y,v1.z,v1.w};
        unsigned short h[8], l[8];
        #pragma unroll
        for (int j = 0; j < 8; j++) split_bf16(vv[j] * sgn, h[j], l[j]);
        #pragma unroll
        for (int j = 0; j < 8; j++) { wbhi[f*8+j] = h[j]; wblo[f*8+j] = l[j]; }
    } else {
        int f = tid - 4096;
        int lane = f & 63, ks = (f >> 6) & 3, nt = (f >> 8) & 3, w = f >> 10;
        int l15 = lane & 15, quad = lane >> 4;
        int n = w * 64 + nt * 16 + l15;
        int d = (n < 128) ? n : (n - 128);
        int k0 = ks * 32 + quad * 8;
        unsigned short h[8];
        #pragma unroll
        for (int j = 0; j < 8; j++) {
            int k = k0 + j, col = k >> 1;
            float val;
            if (n < 128) val = (k & 1) ? -cwi[d * 64 + col] : cwr[d * 64 + col];
            else         val = (k & 1) ?  cwr[d * 64 + col] : cwi[d * 64 + col];
            unsigned short hh, hl; split_bf16(val, hh, hl);
            h[j] = hh;
        }
        #pragma unroll
        for (int j = 0; j < 8; j++) wchi[f*8+j] = h[j];
    }
}

// ============ G1: dt + Bx GEMM + compose. 1 chunk/block, grid 2048 ==========
// bounds(256,4): 64 VGPR -> ALL 8 x-loads hoisted into registers up front
// (8 KB in flight per wave; 16 waves/CU). Single-rail bf16; packed bf16 bx.
#define LDK1 264
__global__ __launch_bounds__(256, 4) void k_g1(
    const float* __restrict__ xr, const float* __restrict__ xi,
    const float* __restrict__ dtw, const float* __restrict__ dtb,
    const float* __restrict__ logAm, const float* __restrict__ Aph,
    const unsigned short* __restrict__ wbhi,
    unsigned* __restrict__ bxp,
    float* __restrict__ dt_mag, float* __restrict__ dt_ph,
    float4* __restrict__ trans)
{
    __shared__ __align__(16) unsigned short Ahi[32 * LDK1];   // 16,896 B
    __shared__ float4 comb[192];                               // 3,072 B
    __shared__ float dms[32], dps[32];                         // 256 B
    float* bxs = (float*)Ahi;   // 32*132 floats, reused after MFMA
    const int t = threadIdx.x;
    const int lane = t & 63, w = t >> 6;
    const int l15 = lane & 15, quad = lane >> 4;
    const int bg = blockIdx.x >> 6, c = blockIdx.x & 63;
    const int g = bg & 7, b = bg >> 3;
    const int crow = (bg * CH + c) * CLEN;

    const float* xrb = xr + ((size_t)(b * S_ + c * CLEN) * G_ + g) * 128;
    const float* xib = xi + ((size_t)(b * S_ + c * CLEN) * G_ + g) * 128;

    // -------- burst-issue ALL x loads first (8 x 1KB/wave in flight) -------
    float4 XA[4], XB[4];
    #pragma unroll
    for (int i = 0; i < 4; i++) {
        int f = t + 256 * i;
        int m = f >> 5, kk = f & 31;
        XA[i] = ((const float4*)(xrb + m * 1024))[kk];
        XB[i] = ((const float4*)(xib + m * 1024))[kk];
    }

    const int kq = t & 31, k4 = kq * 4;
    float4 w0r = *(const float4*)(dtw + k4);
    float4 w0i = *(const float4*)(dtw + 128 + k4);
    float4 w1r = *(const float4*)(dtw + 256 + k4);
    float4 w1i = *(const float4*)(dtw + 384 + k4);
    float b0 = dtb[0], b1 = dtb[1];
    float nla = -logf(1.0f + __expf(logAm[g * N_ + lane]));
    float aph = Aph[g * N_ + lane];

    const bf16x8* WHp = (const bf16x8*)wbhi + (w * 2) * 512 + lane;
    bf16x8 wh0 = WHp[0];
    bf16x8 wh1 = WHp[512];

    // -------- stage x -> LDS (bf16 hi rail) + dt partial dots --------
    float pm[4], pp[4];
    #pragma unroll
    for (int i = 0; i < 4; i++) {
        int f = t + 256 * i;
        int m = f >> 5, kk = f & 31;
        float4 a  = XA[i];
        float4 bb = XB[i];
        *(uint2*)&Ahi[m * LDK1 + kk * 4] =
            make_uint2(pk_bf16(a.x, a.y), pk_bf16(a.z, a.w));
        *(uint2*)&Ahi[m * LDK1 + 128 + kk * 4] =
            make_uint2(pk_bf16(bb.x, bb.y), pk_bf16(bb.z, bb.w));
        pm[i] = dot4(a, w0r) + dot4(bb, w0i);
        pp[i] = dot4(a, w1r) + dot4(bb, w1i);
    }
    #pragma unroll
    for (int i = 0; i < 4; i++) {
        float vm = pm[i], vp = pp[i];
        #pragma unroll
        for (int msk = 16; msk >= 1; msk >>= 1) {
            vm += __shfl_xor(vm, msk);
            vp += __shfl_xor(vp, msk);
        }
        if ((t & 31) == 0) {
            int m = (t >> 5) + 8 * i;
            float dm = fminf(fmaxf(__expf(vm + b0), 1e-4f), 2.0f);
            float dp = fminf(fmaxf(__expf(vp + b1), 1e-4f), 2.0f);
            dms[m] = dm; dps[m] = dp;
            dt_mag[crow + m] = dm; dt_ph[crow + m] = dp;
        }
    }
    __syncthreads();

    // -------- Bx GEMM: 1 MFMA per (ks,ms,nt); W streamed, pipelined --------
    f32x4 acc[2][2];
    #pragma unroll
    for (int a = 0; a < 2; a++)
        #pragma unroll
        for (int bq = 0; bq < 2; bq++)
            acc[a][bq] = (f32x4){0.f, 0.f, 0.f, 0.f};
    #pragma unroll
    for (int ks = 0; ks < 8; ks++) {
        bf16x8 nh0, nh1;
        if (ks < 7) {
            nh0 = WHp[(ks + 1) * 64];
            nh1 = WHp[512 + (ks + 1) * 64];
        }
        #pragma unroll
        for (int ms = 0; ms < 2; ms++) {
            int arow = (ms * 16 + l15) * LDK1 + quad * 8;
            bf16x8 ah = *(const bf16x8*)&Ahi[arow + ks * 32];
            acc[ms][0] = MFMA16(ah, wh0, acc[ms][0]);
            acc[ms][1] = MFMA16(ah, wh1, acc[ms][1]);
        }
        if (ks < 7) { wh0 = nh0; wh1 = nh1; }
    }
    __syncthreads();   // staging reads done; Ahi becomes bxs

    // -------- bx (scaled) -> LDS fp32 --------
    #pragma unroll
    for (int ms = 0; ms < 2; ms++)
        #pragma unroll
        for (int nt = 0; nt < 2; nt++) {
            int n = w * 32 + nt * 16 + l15;
            #pragma unroll
            for (int r = 0; r < 4; r++) {
                int m = ms * 16 + quad * 4 + r;
                bxs[m * 132 + n] = acc[ms][nt][r] * dms[m];
            }
        }
    __syncthreads();

    // -------- packed bf16 bx -> global (contiguous 8KB) + compose ----------
    #pragma unroll
    for (int i = 0; i < 8; i++) {
        int e = t + 256 * i;                 // 2048 = 32 rows x 64 n
        int m = e >> 6, n = e & 63;
        bxp[(crow + m) * 64 + n] = pk_bf16(bxs[m * 132 + n], bxs[m * 132 + 64 + n]);
    }
    {
        float Ar = 1.f, Ai = 0.f, Br = 0.f, Bi = 0.f;
        const int base = w * 8;
        #pragma unroll
        for (int tt = 0; tt < 8; tt++) {
            const int m = base + tt;
            float dm = dms[m], dp = dps[m];
            float am  = __expf(dm * nla);
            float ang = dp * aph;
            float cr = am * __cosf(ang), ci = am * __sinf(ang);
            float vr = bxs[m * 132 + lane], vi = bxs[m * 132 + 64 + lane];
            float nAr = cr * Ar - ci * Ai;
            float nAi = cr * Ai + ci * Ar;
            float nBr = cr * Br - ci * Bi + vr;
            float nBi = cr * Bi + ci * Br + vi;
            Ar = nAr; Ai = nAi; Br = nBr; Bi = nBi;
        }
        if (w < 3) comb[w * 64 + lane] = make_float4(Ar, Ai, Br, Bi);
        __syncthreads();
        if (w == 3) {
            float4 cc0 = comb[lane];
            float cAr = cc0.x, cAi = cc0.y, cBr = cc0.z, cBi = cc0.w;
            #pragma unroll
            for (int s = 1; s < 3; s++) {
                float4 ps = comb[s * 64 + lane];
                float nAr = ps.x * cAr - ps.y * cAi;
                float nAi = ps.x * cAi + ps.y * cAr;
                float nBr = ps.x * cBr - ps.y * cBi + ps.z;
                float nBi = ps.x * cBi + ps.y * cBr + ps.w;
                cAr = nAr; cAi = nAi; cBr = nBr; cBi = nBi;
            }
            float fAr = Ar * cAr - Ai * cAi;
            float fAi = Ar * cAi + Ai * cAr;
            float fBr = Ar * cBr - Ai * cBi + Br;
            float fBi = Ar * cBi + Ai * cBr + Bi;
            trans[(bg * CH + c) * 64 + lane] = make_float4(fAr, fAi, fBr, fBi);
        }
    }
}

// ============ scanB2: parallel chunk-level combine ==========================
__global__ __launch_bounds__(256) void k_scanB2(const float4* __restrict__ trans,
    float2* __restrict__ hstart)
{
    int w = threadIdx.x >> 6, lane = threadIdx.x & 63;
    int W = blockIdx.x * 4 + w;              // [0,256)
    int bg = W >> 3;
    int n  = ((W & 7) << 3) + (lane & 7);
    int j  = lane >> 3;                       // segment index
    float pAr[8], pAi[8], pBr[8], pBi[8];
    float Ar = 1.f, Ai = 0.f, Br = 0.f, Bi = 0.f;
    const float4* tp = trans + (bg * CH + j * 8) * 64 + n;
    #pragma unroll
    for (int k = 0; k < 8; k++) {
        pAr[k] = Ar; pAi[k] = Ai; pBr[k] = Br; pBi[k] = Bi;
        float4 T = tp[k * 64];
        float nAr = T.x * Ar - T.y * Ai;
        float nAi = T.x * Ai + T.y * Ar;
        float nBr = T.x * Br - T.y * Bi + T.z;
        float nBi = T.x * Bi + T.y * Br + T.w;
        Ar = nAr; Ai = nAi; Br = nBr; Bi = nBi;
    }
    float hr = 0.f, hi = 0.f, mhr = 0.f, mhi = 0.f;
    #pragma unroll
    for (int j2 = 0; j2 < 8; j2++) {
        if (j2 == j) { mhr = hr; mhi = hi; }
        int src = j2 * 8 + (lane & 7);
        float sAr = __shfl(Ar, src), sAi = __shfl(Ai, src);
        float sBr = __shfl(Br, src), sBi = __shfl(Bi, src);
        float nr = sAr * hr - sAi * hi + sBr;
        float ni = sAr * hi + sAi * hr + sBi;
        float nrm = sqrtf(nr * nr + ni * ni + 1e-8f);
        float sc = fminf(nrm, 100.f) / nrm;
        hr = nr * sc; hi = ni * sc;
    }
    float2* hp = hstart + (bg * CH + j * 8) * 64 + n;
    #pragma unroll
    for (int k = 0; k < 8; k++) {
        float hsr = pAr[k] * mhr - pAi[k] * mhi + pBr[k];
        float hsi = pAr[k] * mhi + pAi[k] * mhr + pBi[k];
        hp[k * 64] = make_float2(hsr, hsi);
    }
}

// ============ SG5: 4-wave segmented scan + y GEMM, DIRECT stores ============
#define LDK2 152
__global__ __launch_bounds__(256, 6) void k_sg5(
    const unsigned* __restrict__ bxp,
    const float* __restrict__ dt_mag, const float* __restrict__ dt_ph,
    const float* __restrict__ logAm, const float* __restrict__ Aph,
    const float2* __restrict__ hstart,
    const unsigned short* __restrict__ wchi,
    float* __restrict__ out)
{
    __shared__ __align__(16) unsigned short Ahi[32 * LDK2];   // 9,728 B
    __shared__ __align__(16) unsigned short Alo[32 * LDK2];   // 9,728 B
    __shared__ float4 comb[256];                              // 4,096 B
    const int t = threadIdx.x;
    const int lane = t & 63, w = t >> 6;
    const int l15 = lane & 15, quad = lane >> 4;
    const int bg = blockIdx.x >> 6, c = blockIdx.x & 63;
    const int g = bg & 7, b = bg >> 3;
    const int base = (bg * CH + c) * CLEN;
    const int s8 = w * 8;

    // -------- prefetch (independent loads, issued up front) ---------------
    unsigned bxv[8];
    #pragma unroll
    for (int s = 0; s < 8; s++)
        bxv[s] = bxp[(base + s8 + s) * 64 + lane];
    float dval = 0.f;
    if (lane < 8)       dval = dt_mag[base + s8 + lane];
    else if (lane < 16) dval = dt_ph[base + s8 + (lane - 8)];
    float2 h0 = hstart[(bg * CH + c) * 64 + lane];
    float nla = -logf(1.0f + __expf(logAm[g * N_ + lane]));
    float aph = Aph[g * N_ + lane];

    // -------- segment prefix composition (8 steps, in registers) ----------
    float paR[8], paI[8], pbR[8], pbI[8];
    {
        float Ar = 1.f, Ai = 0.f, Br = 0.f, Bi = 0.f;
        #pragma unroll
        for (int s = 0; s < 8; s++) {
            float dm = __shfl(dval, s), dp = __shfl(dval, 8 + s);
            float am  = __expf(dm * nla);
            float ang = dp * aph;
            float cr = am * __cosf(ang), ci = am * __sinf(ang);
            unsigned u = bxv[s];
            float vr = __uint_as_float(u << 16);
            float vi = __uint_as_float(u & 0xFFFF0000u);
            float nAr = cr * Ar - ci * Ai;
            float nAi = cr * Ai + ci * Ar;
            float nBr = cr * Br - ci * Bi + vr;
            float nBi = cr * Bi + ci * Br + vi;
            Ar = nAr; Ai = nAi; Br = nBr; Bi = nBi;
            paR[s] = Ar; paI[s] = Ai; pbR[s] = Br; pbI[s] = Bi;
        }
        comb[w * 64 + lane] = make_float4(Ar, Ai, Br, Bi);
    }
    __syncthreads();

    // -------- lookback + materialize h rows -------------------------------
    float Hr = h0.x, Hi = h0.y;
    for (int s2 = 0; s2 < w; s2++) {           // wave-uniform bound
        float4 T = comb[s2 * 64 + lane];
        float nr = T.x * Hr - T.y * Hi + T.z;
        float ni = T.x * Hi + T.y * Hr + T.w;
        Hr = nr; Hi = ni;
    }
    {
        const bool rn = ((c & 7) == 7) && (w == 3);
        #pragma unroll
        for (int s = 0; s < 8; s++) {
            float hr = paR[s] * Hr - paI[s] * Hi + pbR[s];
            float hi = paR[s] * Hi + paI[s] * Hr + pbI[s];
            if (rn && s == 7) {
                float nrm = sqrtf(hr * hr + hi * hi + 1e-8f);
                float scale = fminf(nrm, 100.0f) / nrm;
                hr *= scale; hi *= scale;
            }
            unsigned hp = pk_bf16(hr, hi);
            float rr = hr - __uint_as_float(hp << 16);
            float ri = hi - __uint_as_float(hp & 0xFFFF0000u);
            unsigned lp = pk_bf16(rr, ri);
            int tt = s8 + s;
            *(unsigned*)&Ahi[tt * LDK2 + 2 * lane] = hp;
            *(unsigned*)&Alo[tt * LDK2 + 2 * lane] = lp;
        }
    }
    __syncthreads();

    // -------- y GEMM: M=32, N=256 (wave owns 64 cols), wc streamed ---------
    f32x4 acc[2][4];
    #pragma unroll
    for (int a = 0; a < 2; a++)
        #pragma unroll
        for (int bq = 0; bq < 4; bq++)
            acc[a][bq] = (f32x4){0.f, 0.f, 0.f, 0.f};
    #pragma unroll
    for (int ks = 0; ks < 4; ks++) {
        bf16x8 wc0 = ((const bf16x8*)wchi)[((w * 4 + 0) * 4 + ks) * 64 + lane];
        bf16x8 wc1 = ((const bf16x8*)wchi)[((w * 4 + 1) * 4 + ks) * 64 + lane];
        bf16x8 wc2 = ((const bf16x8*)wchi)[((w * 4 + 2) * 4 + ks) * 64 + lane];
        bf16x8 wc3 = ((const bf16x8*)wchi)[((w * 4 + 3) * 4 + ks) * 64 + lane];
        #pragma unroll
        for (int ms = 0; ms < 2; ms++) {
            int arow = (ms * 16 + l15) * LDK2 + quad * 8;
            bf16x8 ah = *(const bf16x8*)&Ahi[arow + ks * 32];
            bf16x8 al = *(const bf16x8*)&Alo[arow + ks * 32];
            acc[ms][0] = MFMA16(al, wc0, acc[ms][0]);
            acc[ms][0] = MFMA16(ah, wc0, acc[ms][0]);
            acc[ms][1] = MFMA16(al, wc1, acc[ms][1]);
            acc[ms][1] = MFMA16(ah, wc1, acc[ms][1]);
            acc[ms][2] = MFMA16(al, wc2, acc[ms][2]);
            acc[ms][2] = MFMA16(ah, wc2, acc[ms][2]);
            acc[ms][3] = MFMA16(al, wc3, acc[ms][3]);
            acc[ms][3] = MFMA16(ah, wc3, acc[ms][3]);
        }
    }
    #pragma unroll
    for (int ms = 0; ms < 2; ms++)
        #pragma unroll
        for (int nt = 0; nt < 4; nt++) {
            int nn = w * 64 + nt * 16 + l15;
            float* dst = (nn < 128) ? (out + nn) : (out + YOFF + (nn - 128));
            #pragma unroll
            for (int r = 0; r < 4; r++) {
                int tt2 = ms * 16 + quad * 4 + r;
                int srow = (b * S_ + c * CLEN + tt2) * G_ + g;
                dst[srow * 128] = acc[ms][nt][r];
            }
        }
}

extern "C" void kernel_launch(void* const* d_in, const int* in_sizes, int n_in,
                              void* d_out, int out_size, void* d_ws, size_t ws_size,
                              hipStream_t stream) {
    (void)in_sizes; (void)n_in; (void)out_size; (void)ws_size;
    const float* xr    = (const float*)d_in[0];
    const float* xi    = (const float*)d_in[1];
    const float* logAm = (const float*)d_in[2];
    const float* Aph   = (const float*)d_in[3];
    const float* bwr   = (const float*)d_in[4];
    const float* bwi   = (const float*)d_in[5];
    const float* cwr   = (const float*)d_in[6];
    const float* cwi   = (const float*)d_in[7];
    const float* dtw   = (const float*)d_in[8];
    const float* dtb   = (const float*)d_in[9];
    float* out = (float*)d_out;
    float* ws  = (float*)d_ws;

    float*    dt_mag = ws;                      // 65536
    float*    dt_ph  = ws + 65536;              // 65536
    unsigned* bxp    = (unsigned*)(ws + 131072);// 4194304 u32 (16 MB)
    float4*   trans  = (float4*)(ws + 8519680); // 131072 float4
    float2*   hstart = (float2*)(ws + 9043968); // 131072 float2
    unsigned short* wbhi = (unsigned short*)(ws + 9306112); // 32768 shorts
    unsigned short* wblo = wbhi + 32768;
    unsigned short* wchi = wblo + 32768;

    hipLaunchKernelGGL(k_prep,   dim3(32), dim3(256), 0, stream,
                       bwr, bwi, cwr, cwi, wbhi, wblo, wchi);
    hipLaunchKernelGGL(k_g1,     dim3((B_ * G_) * 64), dim3(256), 0, stream,
                       xr, xi, dtw, dtb, logAm, Aph, wbhi,
                       bxp, dt_mag, dt_ph, trans);
    hipLaunchKernelGGL(k_scanB2, dim3(64), dim3(256), 0, stream,
                       trans, hstart);
    hipLaunchKernelGGL(k_sg5,    dim3((B_ * G_) * 64), dim3(256), 0, stream,
                       bxp, dt_mag, dt_ph, logAm, Aph, hstart, wchi, out);
}